// Round 1
// baseline (299.828 us; speedup 1.0000x reference)
//
#include <hip/hip_runtime.h>

// Problem constants
#define BATCH 64
#define NNODE 1024
#define FDIM  200
#define MROWS (BATCH * NNODE)   // 65536
#define NEG_SLOPE 0.2f

// ws layout (floats):
//   h0  : [0, 204800)         1024*200
//   a_s : [204800, 205824)
//   a_d : [205824, 206848)
//   m_i : [206848, 207872)
//   l_i : [207872, 208896)
// total 208896 floats = 835,584 bytes

__device__ __forceinline__ float lrelu(float v) {
    return (v > 0.f) ? v : NEG_SLOPE * v;
}

// ---------------------------------------------------------------------------
// Kernel 1: h = x @ W for all 65536 rows.
//   rows <  1024 : write raw h0 to ws (attention consumes it)
//   rows >= 1024 : write h + bias to out
// Block: 256 thr = 4 waves. 64 rows/block. lane = row, wave = 50-col chunk.
// x tile in LDS [k][row] with +1 pad (conflict-free writes AND reads).
// W row-chunk is wave-uniform -> scalar loads (readfirstlane trick).
// ---------------------------------------------------------------------------
__global__ __launch_bounds__(256) void k_gemm(const float* __restrict__ x,
                                              const float* __restrict__ W,
                                              const float* __restrict__ bias,
                                              float* __restrict__ out,
                                              float* __restrict__ h0)
{
    __shared__ float xs[200 * 65];   // 52,000 B: [k][row], pad 65 breaks write conflicts
    const int tid = threadIdx.x;
    const int blk = blockIdx.x;
    const int R0  = blk * 64;

    // stage x tile: 64 rows x 200 k = 12800 floats, 50 per thread, coalesced global
    #pragma unroll
    for (int it = 0; it < 50; ++it) {
        int idx = tid + it * 256;
        int row = idx / 200;
        int k   = idx - row * 200;
        xs[k * 65 + row] = x[(size_t)(R0 + row) * 200 + k];
    }
    __syncthreads();

    const int r  = tid & 63;
    const int w  = __builtin_amdgcn_readfirstlane(tid >> 6);  // wave id, provably uniform
    const int c0 = w * 50;

    float acc[50];
    #pragma unroll
    for (int j = 0; j < 50; ++j) acc[j] = 0.f;

    for (int k = 0; k < 200; ++k) {
        float xv = xs[k * 65 + r];                 // lanes stride-1: conflict-free
        const float* Wk = W + k * 200 + c0;        // wave-uniform -> s_load
        #pragma unroll
        for (int j = 0; j < 50; ++j)
            acc[j] = fmaf(Wk[j], xv, acc[j]);      // v_fmac with SGPR operand
    }

    const int row_g = R0 + r;
    if (R0 >= NNODE) {
        float bl[50];
        const float* bp = bias + c0;               // uniform -> s_load
        #pragma unroll
        for (int j = 0; j < 50; ++j) bl[j] = bp[j];
        float* op = out + (size_t)row_g * 200 + c0;
        #pragma unroll
        for (int j = 0; j < 50; j += 2) {
            float2 v = make_float2(acc[j] + bl[j], acc[j + 1] + bl[j + 1]);
            *reinterpret_cast<float2*>(op + j) = v;
        }
    } else {
        float* hp = h0 + (size_t)row_g * 200 + c0;
        #pragma unroll
        for (int j = 0; j < 50; j += 2) {
            float2 v = make_float2(acc[j], acc[j + 1]);
            *reinterpret_cast<float2*>(hp + j) = v;
        }
    }
}

// ---------------------------------------------------------------------------
// Kernel 1b: a_s = h0 @ att_src, a_d = h0 @ att_dst.  One wave per row.
// ---------------------------------------------------------------------------
__global__ __launch_bounds__(256) void k_attvec(const float* __restrict__ h0,
                                                const float* __restrict__ att_src,
                                                const float* __restrict__ att_dst,
                                                float* __restrict__ a_s,
                                                float* __restrict__ a_d)
{
    const int tid  = threadIdx.x;
    const int lane = tid & 63;
    const int wv   = tid >> 6;
    const int row  = blockIdx.x * 4 + wv;
    const float* hr = h0 + (size_t)row * 200;
    float ss = 0.f, sd = 0.f;
    for (int k = lane; k < 200; k += 64) {
        float hv = hr[k];
        ss = fmaf(hv, att_src[k], ss);
        sd = fmaf(hv, att_dst[k], sd);
    }
    #pragma unroll
    for (int off = 32; off; off >>= 1) {
        ss += __shfl_down(ss, off);
        sd += __shfl_down(sd, off);
    }
    if (lane == 0) { a_s[row] = ss; a_d[row] = sd; }
}

// ---------------------------------------------------------------------------
// Kernel 2a: per-row softmax stats.
// leaky_relu monotone => row max = lrelu(a_d[i] + max_j a_s[j]).
// One wave per row; 4 rows/block.
// ---------------------------------------------------------------------------
__global__ __launch_bounds__(256) void k_stats(const float* __restrict__ a_s,
                                               const float* __restrict__ a_d,
                                               float* __restrict__ m_out,
                                               float* __restrict__ l_out)
{
    __shared__ float as_s[1024];
    const int tid = threadIdx.x;
    #pragma unroll
    for (int i = 0; i < 4; ++i) as_s[tid + i * 256] = a_s[tid + i * 256];
    __syncthreads();

    const int lane = tid & 63;
    const int wv   = tid >> 6;
    const int row  = blockIdx.x * 4 + wv;

    float mx = -1e30f;
    #pragma unroll
    for (int i = 0; i < 16; ++i) mx = fmaxf(mx, as_s[lane + i * 64]);
    #pragma unroll
    for (int off = 32; off; off >>= 1) mx = fmaxf(mx, __shfl_down(mx, off));
    mx = __shfl(mx, 0);

    const float ad = a_d[row];
    const float mi = lrelu(ad + mx);

    float sum = 0.f;
    #pragma unroll
    for (int i = 0; i < 16; ++i) {
        float s = lrelu(ad + as_s[lane + i * 64]);
        sum += __expf(s - mi);
    }
    #pragma unroll
    for (int off = 32; off; off >>= 1) sum += __shfl_down(sum, off);
    if (lane == 0) { m_out[row] = mi; l_out[row] = sum; }
}

// ---------------------------------------------------------------------------
// Kernel 2b: out[i] = bias + sum_j alpha[i][j] * h0[j]  for i in [0,1024).
// Grid 64 blocks = 16 i-tiles x 4 col-chunks. Block: 4 waves = 4 j-quarters.
// lane = i (64 rows), wave-uniform j => a_s[j] and h0-row chunk via s_load.
// alpha computed in registers (exp-weighted, scaled by 1/l at the end).
// Cross-wave (j-quarter) reduction through LDS; no atomics.
// ---------------------------------------------------------------------------
__global__ __launch_bounds__(256) void k_attn(const float* __restrict__ h0,
                                              const float* __restrict__ a_s,
                                              const float* __restrict__ a_d,
                                              const float* __restrict__ m_v,
                                              const float* __restrict__ l_v,
                                              const float* __restrict__ bias,
                                              float* __restrict__ out)
{
    __shared__ float red[4 * 64 * 50];   // 51,200 B
    const int tid  = threadIdx.x;
    const int lane = tid & 63;
    const int w    = __builtin_amdgcn_readfirstlane(tid >> 6);
    const int b    = blockIdx.x;
    const int it   = b >> 2;     // i-tile   [0,16)
    const int cc   = b & 3;      // c-chunk  [0,4)
    const int i_g  = it * 64 + lane;
    const int c0   = cc * 50;

    const float ad = a_d[i_g];
    const float mi = m_v[i_g];
    const float rl = 1.0f / l_v[i_g];

    float acc[50];
    #pragma unroll
    for (int c = 0; c < 50; ++c) acc[c] = 0.f;

    const int j0 = w * 256;
    for (int j = j0; j < j0 + 256; ++j) {
        float s = ad + a_s[j];                       // a_s[j] wave-uniform -> s_load
        s = (s > 0.f) ? s : NEG_SLOPE * s;
        float e = __expf(s - mi);
        const float* hr = h0 + (size_t)j * 200 + c0; // wave-uniform -> s_load
        #pragma unroll
        for (int c = 0; c < 50; ++c)
            acc[c] = fmaf(hr[c], e, acc[c]);
    }

    #pragma unroll
    for (int c = 0; c < 50; ++c)
        red[(w * 64 + lane) * 50 + c] = acc[c] * rl;
    __syncthreads();

    for (int idx = tid; idx < 3200; idx += 256) {
        int i = idx / 50;
        int c = idx - i * 50;
        float v = red[idx] + red[3200 + idx] + red[6400 + idx] + red[9600 + idx];
        out[(size_t)(it * 64 + i) * 200 + c0 + c] = v + bias[c0 + c];
    }
}

// ---------------------------------------------------------------------------
extern "C" void kernel_launch(void* const* d_in, const int* in_sizes, int n_in,
                              void* d_out, int out_size, void* d_ws, size_t ws_size,
                              hipStream_t stream)
{
    const float* x       = (const float*)d_in[0];
    const float* W       = (const float*)d_in[1];
    const float* att_src = (const float*)d_in[2];
    const float* att_dst = (const float*)d_in[3];
    const float* bias    = (const float*)d_in[4];
    float* out = (float*)d_out;
    float* ws  = (float*)d_ws;

    float* h0  = ws;              // 204800 floats
    float* a_s = ws + 204800;     // 1024
    float* a_d = a_s + 1024;      // 1024
    float* m_i = a_d + 1024;      // 1024
    float* l_i = m_i + 1024;      // 1024

    k_gemm  <<<MROWS / 64, 256, 0, stream>>>(x, W, bias, out, h0);
    k_attvec<<<NNODE / 4,  256, 0, stream>>>(h0, att_src, att_dst, a_s, a_d);
    k_stats <<<NNODE / 4,  256, 0, stream>>>(a_s, a_d, m_i, l_i);
    k_attn  <<<64,         256, 0, stream>>>(h0, a_s, a_d, m_i, l_i, bias, out);
}

// Round 2
// 159.559 us; speedup vs baseline: 1.8791x; 1.8791x over previous
//
#include <hip/hip_runtime.h>

// Problem constants
#define BATCH 64
#define NNODE 1024
#define FDIM  200
#define MROWS (BATCH * NNODE)   // 65536
#define NEG_SLOPE 0.2f

// Padded GEMM dims for 16x16x32 bf16 MFMA
#define KPAD 224                // 7 k-tiles of 32
#define NPAD 208                // 13 n-tiles of 16
#define NKT 7
#define NNT 13
#define XS_STRIDE 232           // bf16 row stride: 464 B = 29*16 (16B aligned), 2-way banks (free)

typedef short s16x8 __attribute__((ext_vector_type(8)));
typedef float f32x4 __attribute__((ext_vector_type(4)));

// ws layout:
//   h0    : float [0, 204800)
//   a_s   : float [204800, 205824)
//   a_d   : float [205824, 206848)
//   m_i   : float [206848, 207872)
//   l_i   : float [207872, 208896)
//   fragW : bf16  at byte offset 835584 (16B aligned), 91*512 elems = 93,184 B

__device__ __forceinline__ float lrelu(float v) {
    return (v > 0.f) ? v : NEG_SLOPE * v;
}

// fp32 -> bf16 bits, round-to-nearest-even
__device__ __forceinline__ unsigned int f2bf(float f) {
    unsigned int u = __float_as_uint(f);
    return (u + 0x7fffu + ((u >> 16) & 1u)) >> 16;
}
__device__ __forceinline__ unsigned int pack2(float a, float b) {
    return f2bf(a) | (f2bf(b) << 16);
}

// ---------------------------------------------------------------------------
// k_prep: repack W (200x200 fp32) into bf16 B-fragment layout for 16x16x32:
//   lane holds B[k = kt*32 + (lane>>4)*8 + j][n = nt*16 + (lane&15)], j=0..7
//   fragW[(kt*13+nt)*512 + lane*8 + j], zero-padded past 200.
// 91 blocks x 64 threads.
// ---------------------------------------------------------------------------
__global__ __launch_bounds__(64) void k_prep(const float* __restrict__ W,
                                             unsigned short* __restrict__ fragW)
{
    const int b    = blockIdx.x;          // kt*13 + nt
    const int kt   = b / NNT;
    const int nt   = b - kt * NNT;
    const int lane = threadIdx.x;
    const int n    = nt * 16 + (lane & 15);
    const int kb   = kt * 32 + (lane >> 4) * 8;

    s16x8 v;
    #pragma unroll
    for (int j = 0; j < 8; ++j) {
        int k = kb + j;
        float f = (k < FDIM && n < FDIM) ? W[k * FDIM + n] : 0.f;
        v[j] = (short)f2bf(f);
    }
    s16x8* dst = (s16x8*)(fragW + (size_t)b * 512);
    dst[lane] = v;
}

// ---------------------------------------------------------------------------
// k_gemm: h = x @ W via bf16 MFMA. 1024 blocks x 64 rows, 4 waves.
// Wave w computes rows w*16..w*16+15 across all 13 n-tiles (52 acc VGPRs).
//   blocks 0..15   (rows < 1024): raw fp32 h -> ws h0; bias -> out (atomics seed)
//   blocks 16..1023: h + bias -> out
// ---------------------------------------------------------------------------
__global__ __launch_bounds__(256) void k_gemm(const float* __restrict__ x,
                                              const unsigned short* __restrict__ fragW,
                                              const float* __restrict__ bias,
                                              float* __restrict__ out,
                                              float* __restrict__ h0)
{
    __shared__ __align__(16) unsigned short xs[64 * XS_STRIDE];  // 29,696 B
    const int tid = threadIdx.x;
    const int R0  = blockIdx.x * 64;

    // ---- stage x tile as bf16: thread t -> row t>>2, k-chunk (t&3)*50..+49
    {
        const int row = tid >> 2;
        const int q   = tid & 3;
        const float2* xp2 = (const float2*)(x + (size_t)(R0 + row) * FDIM + q * 50);
        unsigned int* xsrow = (unsigned int*)(xs + row * XS_STRIDE);
        const int du = q * 25;  // dword offset into row
        #pragma unroll
        for (int i = 0; i < 25; ++i) {
            float2 v = xp2[i];
            xsrow[du + i] = pack2(v.x, v.y);
        }
        if (q == 3) {  // zero-pad k in [200, 232)
            #pragma unroll
            for (int i = 0; i < 16; ++i) xsrow[100 + i] = 0u;
        }
    }
    __syncthreads();

    const int lane = tid & 63;
    const int w    = __builtin_amdgcn_readfirstlane(tid >> 6);
    const int ln   = lane & 15;
    const int quad = lane >> 4;

    f32x4 acc[NNT];
    #pragma unroll
    for (int nt = 0; nt < NNT; ++nt) acc[nt] = (f32x4){0.f, 0.f, 0.f, 0.f};

    const unsigned short* xrow = xs + (w * 16 + ln) * XS_STRIDE;

    #pragma unroll
    for (int kt = 0; kt < NKT; ++kt) {
        s16x8 a = *(const s16x8*)(xrow + kt * 32 + quad * 8);
        #pragma unroll
        for (int nt = 0; nt < NNT; ++nt) {
            s16x8 bf = *(const s16x8*)(fragW + ((size_t)(kt * NNT + nt) * 512 + lane * 8));
            acc[nt] = __builtin_amdgcn_mfma_f32_16x16x32_bf16(a, bf, acc[nt], 0, 0, 0);
        }
    }

    // ---- epilogue. D layout: col = nt*16 + (lane&15), row = quad*4 + reg
    const int rbase = R0 + w * 16 + quad * 4;
    if (R0 >= NNODE) {
        #pragma unroll
        for (int nt = 0; nt < NNT; ++nt) {
            int col = nt * 16 + ln;
            if (nt < 12 || ln < 8) {
                float bv = bias[col];
                #pragma unroll
                for (int reg = 0; reg < 4; ++reg)
                    out[(size_t)(rbase + reg) * FDIM + col] = acc[nt][reg] + bv;
            }
        }
    } else {
        #pragma unroll
        for (int nt = 0; nt < NNT; ++nt) {
            int col = nt * 16 + ln;
            if (nt < 12 || ln < 8) {
                #pragma unroll
                for (int reg = 0; reg < 4; ++reg)
                    h0[(size_t)(rbase + reg) * FDIM + col] = acc[nt][reg];
            }
        }
        // seed out rows [R0, R0+64) with bias (k_attn atomically accumulates)
        const int row = tid >> 2;
        const int q   = tid & 3;
        float* op = out + (size_t)(R0 + row) * FDIM + q * 50;
        const float* bp = bias + q * 50;
        #pragma unroll
        for (int i = 0; i < 50; ++i) op[i] = bp[i];
    }
}

// ---------------------------------------------------------------------------
// k_attvec: a_s = h0 @ att_src, a_d = h0 @ att_dst.  One wave per row.
// ---------------------------------------------------------------------------
__global__ __launch_bounds__(256) void k_attvec(const float* __restrict__ h0,
                                                const float* __restrict__ att_src,
                                                const float* __restrict__ att_dst,
                                                float* __restrict__ a_s,
                                                float* __restrict__ a_d)
{
    const int tid  = threadIdx.x;
    const int lane = tid & 63;
    const int wv   = tid >> 6;
    const int row  = blockIdx.x * 4 + wv;
    const float* hr = h0 + (size_t)row * FDIM;
    float ss = 0.f, sd = 0.f;
    for (int k = lane; k < FDIM; k += 64) {
        float hv = hr[k];
        ss = fmaf(hv, att_src[k], ss);
        sd = fmaf(hv, att_dst[k], sd);
    }
    #pragma unroll
    for (int off = 32; off; off >>= 1) {
        ss += __shfl_down(ss, off);
        sd += __shfl_down(sd, off);
    }
    if (lane == 0) { a_s[row] = ss; a_d[row] = sd; }
}

// ---------------------------------------------------------------------------
// k_stats: per-row softmax stats. lrelu monotone => row max = lrelu(ad + max a_s).
// ---------------------------------------------------------------------------
__global__ __launch_bounds__(256) void k_stats(const float* __restrict__ a_s,
                                               const float* __restrict__ a_d,
                                               float* __restrict__ m_out,
                                               float* __restrict__ l_out)
{
    __shared__ float as_s[1024];
    const int tid = threadIdx.x;
    #pragma unroll
    for (int i = 0; i < 4; ++i) as_s[tid + i * 256] = a_s[tid + i * 256];
    __syncthreads();

    const int lane = tid & 63;
    const int wv   = tid >> 6;
    const int row  = blockIdx.x * 4 + wv;

    float mx = -1e30f;
    #pragma unroll
    for (int i = 0; i < 16; ++i) mx = fmaxf(mx, as_s[lane + i * 64]);
    #pragma unroll
    for (int off = 32; off; off >>= 1) mx = fmaxf(mx, __shfl_down(mx, off));
    mx = __shfl(mx, 0);

    const float ad = a_d[row];
    const float mi = lrelu(ad + mx);

    float sum = 0.f;
    #pragma unroll
    for (int i = 0; i < 16; ++i) {
        float s = lrelu(ad + as_s[lane + i * 64]);
        sum += __expf(s - mi);
    }
    #pragma unroll
    for (int off = 32; off; off >>= 1) sum += __shfl_down(sum, off);
    if (lane == 0) { m_out[row] = mi; l_out[row] = sum; }
}

// ---------------------------------------------------------------------------
// k_attn: out[i] += sum_j alpha[i][j] * h0[j] (bias pre-seeded by k_gemm).
// 256 blocks = 16 i-tiles x 4 col-chunks x 4 j-splits. Waves sub-split j (64 each).
// lane = i; wave-uniform j => a_s[j] / h0-row chunk via s_load.
// LDS cross-wave reduce, then fp32 atomicAdd (4 blocks per address).
// ---------------------------------------------------------------------------
__global__ __launch_bounds__(256) void k_attn(const float* __restrict__ h0,
                                              const float* __restrict__ a_s,
                                              const float* __restrict__ a_d,
                                              const float* __restrict__ m_v,
                                              const float* __restrict__ l_v,
                                              float* __restrict__ out)
{
    __shared__ float red[4 * 64 * 50];   // 51,200 B
    const int tid  = threadIdx.x;
    const int lane = tid & 63;
    const int w    = __builtin_amdgcn_readfirstlane(tid >> 6);
    const int b    = blockIdx.x;
    const int it   = b >> 4;          // i-tile  [0,16)
    const int cc   = (b >> 2) & 3;    // c-chunk [0,4)
    const int js   = b & 3;           // j-split [0,4)
    const int i_g  = it * 64 + lane;
    const int c0   = cc * 50;

    const float ad = a_d[i_g];
    const float mi = m_v[i_g];
    const float rl = 1.0f / l_v[i_g];

    float acc[50];
    #pragma unroll
    for (int c = 0; c < 50; ++c) acc[c] = 0.f;

    const int j0 = js * 256 + w * 64;
    for (int j = j0; j < j0 + 64; ++j) {
        float s = ad + a_s[j];                        // wave-uniform -> s_load
        s = (s > 0.f) ? s : NEG_SLOPE * s;
        float e = __expf(s - mi);
        const float* hr = h0 + (size_t)j * FDIM + c0; // wave-uniform -> s_load
        #pragma unroll
        for (int c = 0; c < 50; ++c)
            acc[c] = fmaf(hr[c], e, acc[c]);
    }

    #pragma unroll
    for (int c = 0; c < 50; ++c)
        red[(w * 64 + lane) * 50 + c] = acc[c] * rl;
    __syncthreads();

    for (int idx = tid; idx < 3200; idx += 256) {
        int i = idx / 50;
        int c = idx - i * 50;
        float v = red[idx] + red[3200 + idx] + red[6400 + idx] + red[9600 + idx];
        atomicAdd(out + (size_t)(it * 64 + i) * FDIM + c0 + c, v);
    }
}

// ---------------------------------------------------------------------------
extern "C" void kernel_launch(void* const* d_in, const int* in_sizes, int n_in,
                              void* d_out, int out_size, void* d_ws, size_t ws_size,
                              hipStream_t stream)
{
    const float* x       = (const float*)d_in[0];
    const float* W       = (const float*)d_in[1];
    const float* att_src = (const float*)d_in[2];
    const float* att_dst = (const float*)d_in[3];
    const float* bias    = (const float*)d_in[4];
    float* out = (float*)d_out;
    float* ws  = (float*)d_ws;

    float* h0  = ws;              // 204800 floats
    float* a_s = ws + 204800;     // 1024
    float* a_d = a_s + 1024;      // 1024
    float* m_i = a_d + 1024;      // 1024
    float* l_i = m_i + 1024;      // 1024
    unsigned short* fragW = (unsigned short*)((char*)d_ws + 835584);  // 93,184 B

    k_prep  <<<NKT * NNT,  64, 0, stream>>>(W, fragW);
    k_gemm  <<<MROWS / 64, 256, 0, stream>>>(x, fragW, bias, out, h0);
    k_attvec<<<NNODE / 4,  256, 0, stream>>>(h0, att_src, att_dst, a_s, a_d);
    k_stats <<<NNODE / 4,  256, 0, stream>>>(a_s, a_d, m_i, l_i);
    k_attn  <<<256,        256, 0, stream>>>(h0, a_s, a_d, m_i, l_i, out);
}

// Round 4
// 158.265 us; speedup vs baseline: 1.8945x; 1.0082x over previous
//
#include <hip/hip_runtime.h>

// Problem constants
#define BATCH 64
#define NNODE 1024
#define FDIM  200
#define MROWS (BATCH * NNODE)   // 65536
#define NEG_SLOPE 0.2f

// GEMM padding for 16x16x32 bf16 MFMA
#define NKT 7                   // 7 k-tiles of 32  (K 200 -> 224)
#define NNT 16                  // 16 n-tiles of 16 (N 200 -> 256), 4 per wave
#define XS_STRIDE 232           // bf16 row stride: 464 B, 16B-aligned

typedef short s16x8 __attribute__((ext_vector_type(8)));
typedef float f32x4 __attribute__((ext_vector_type(4)));

// ws layout:
//   h0    : float [0, 204800)
//   a_s   : float [204800, 205824)   (atomic-accumulated; zeroed by k_prep)
//   a_d   : float [205824, 206848)
//   m_i   : float [206848, 207872)
//   l_i   : float [207872, 208896)
//   fragW : bf16  at byte 835584, 112*512 elems = 114,688 B

__device__ __forceinline__ float lrelu(float v) {
    return (v > 0.f) ? v : NEG_SLOPE * v;
}
__device__ __forceinline__ unsigned int f2bf(float f) {
    unsigned int u = __float_as_uint(f);
    return (u + 0x7fffu + ((u >> 16) & 1u)) >> 16;
}
__device__ __forceinline__ unsigned int pack2(float a, float b) {
    return f2bf(a) | (f2bf(b) << 16);
}

// ---------------------------------------------------------------------------
// k_prep: W (200x200 fp32) -> bf16 B-fragments, padded to 224x256.
//   frag b = kt*16+nt: lane holds B[k=kt*32+(lane>>4)*8+j][n=nt*16+(lane&15)]
// Block 0 also zeroes a_s/a_d (atomic targets).
// ---------------------------------------------------------------------------
__global__ __launch_bounds__(64) void k_prep(const float* __restrict__ W,
                                             unsigned short* __restrict__ fragW,
                                             float* __restrict__ a_s,
                                             float* __restrict__ a_d)
{
    const int b    = blockIdx.x;          // kt*16 + nt, 112 blocks
    const int kt   = b >> 4;
    const int nt   = b & 15;
    const int lane = threadIdx.x;
    const int n    = nt * 16 + (lane & 15);
    const int kb   = kt * 32 + (lane >> 4) * 8;

    s16x8 v;
    #pragma unroll
    for (int j = 0; j < 8; ++j) {
        int k = kb + j;
        float f = (k < FDIM && n < FDIM) ? W[k * FDIM + n] : 0.f;
        v[j] = (short)f2bf(f);
    }
    ((s16x8*)(fragW + (size_t)b * 512))[lane] = v;

    if (b == 0) {
        for (int i = lane; i < NNODE; i += 64) { a_s[i] = 0.f; a_d[i] = 0.f; }
    }
}

// ---------------------------------------------------------------------------
// k_gemm: h = x @ W via bf16 MFMA, B held in VGPRs for the whole kernel.
// Grid 512 blocks x 256 thr (4 waves); block = 128 rows = 2 tiles of 64.
// Wave w owns n-tiles [4w, 4w+4) = cols [64w, 64w+64). B-frags: 28 x 4 VGPR.
// Per tile: stage x (64x200 fp32 -> bf16 LDS, coalesced float4), then
// 4 subtiles x 7 kt x 4 nt MFMA (acc = 64 VGPR).
//   R0 <  1024: h -> ws h0; fused a_s/a_d dot partials (shuffle + atomics);
//               bias seeded into out (k_attn atomically accumulates).
//   R0 >= 1024: h + bias -> out.
// ---------------------------------------------------------------------------
__global__ __launch_bounds__(256, 2) void k_gemm(const float* __restrict__ x,
                                                 const unsigned short* __restrict__ fragW,
                                                 const float* __restrict__ bias,
                                                 const float* __restrict__ att_src,
                                                 const float* __restrict__ att_dst,
                                                 float* __restrict__ out,
                                                 float* __restrict__ h0,
                                                 float* __restrict__ a_s,
                                                 float* __restrict__ a_d)
{
    __shared__ __align__(16) unsigned short xs[64 * XS_STRIDE];  // 29,696 B
    const int tid  = threadIdx.x;
    const int lane = tid & 63;
    const int w    = __builtin_amdgcn_readfirstlane(tid >> 6);
    const int ln   = lane & 15;
    const int quad = lane >> 4;

    // ---- B fragments: loaded once, live in VGPRs (28 x 16B = 112 VGPR)
    s16x8 bfr[NKT][4];
    #pragma unroll
    for (int kt = 0; kt < NKT; ++kt)
        #pragma unroll
        for (int nt = 0; nt < 4; ++nt)
            bfr[kt][nt] = *(const s16x8*)(fragW +
                ((size_t)(kt * NNT + w * 4 + nt) * 512 + lane * 8));

    for (int t = 0; t < 2; ++t) {
        const int R0 = blockIdx.x * 128 + t * 64;
        if (t) __syncthreads();   // xs reuse: wait for all waves' reads of tile 0

        // ---- stage x tile: flat float4, consecutive lanes -> consecutive 16B
        {
            const float4* xp = (const float4*)(x + (size_t)R0 * FDIM);
            #pragma unroll
            for (int i = 0; i < 13; ++i) {
                int f = tid + i * 256;               // float4 index, 3200 total
                if (i < 12 || f < 3200) {
                    float4 v = xp[f];
                    int row = f / 50;                // 50 float4 per row
                    int c4  = f - row * 50;
                    unsigned int* dst = (unsigned int*)(xs + row * XS_STRIDE + c4 * 4);
                    dst[0] = pack2(v.x, v.y);
                    dst[1] = pack2(v.z, v.w);
                }
            }
            // zero-pad k in [200, 232): 4 threads/row, 16 B (8 shorts) each
            // short-offset 200+seg*8, byte-offset 400+seg*16 from 16B-aligned row
            int row = tid >> 2, seg = tid & 3;
            *(int4*)(xs + row * XS_STRIDE + 200 + seg * 8) = make_int4(0, 0, 0, 0);
        }
        __syncthreads();

        // ---- MFMA: 4 row-subtiles x 7 kt x 4 nt
        f32x4 acc[4][4];
        #pragma unroll
        for (int s = 0; s < 4; ++s)
            #pragma unroll
            for (int nt = 0; nt < 4; ++nt) acc[s][nt] = (f32x4){0.f, 0.f, 0.f, 0.f};

        #pragma unroll
        for (int s = 0; s < 4; ++s) {
            const unsigned short* xrow = xs + (s * 16 + ln) * XS_STRIDE + quad * 8;
            #pragma unroll
            for (int kt = 0; kt < NKT; ++kt) {
                s16x8 a = *(const s16x8*)(xrow + kt * 32);
                #pragma unroll
                for (int nt = 0; nt < 4; ++nt)
                    acc[s][nt] = __builtin_amdgcn_mfma_f32_16x16x32_bf16(
                        a, bfr[kt][nt], acc[s][nt], 0, 0, 0);
            }
        }

        // ---- epilogue. D: col = 64w + nt*16 + ln, row = s*16 + quad*4 + reg
        if (R0 >= NNODE) {
            #pragma unroll
            for (int nt = 0; nt < 4; ++nt) {
                int col = w * 64 + nt * 16 + ln;
                if (col < FDIM) {
                    float bv = bias[col];
                    #pragma unroll
                    for (int s = 0; s < 4; ++s)
                        #pragma unroll
                        for (int r = 0; r < 4; ++r)
                            out[(size_t)(R0 + s * 16 + quad * 4 + r) * FDIM + col]
                                = acc[s][nt][r] + bv;
                }
            }
        } else {
            float asv[4], adv[4];
            #pragma unroll
            for (int nt = 0; nt < 4; ++nt) {
                int col = w * 64 + nt * 16 + ln;
                asv[nt] = 0.f; adv[nt] = 0.f;
                if (col < FDIM) {
                    asv[nt] = att_src[col]; adv[nt] = att_dst[col];
                    #pragma unroll
                    for (int s = 0; s < 4; ++s)
                        #pragma unroll
                        for (int r = 0; r < 4; ++r)
                            h0[(size_t)(R0 + s * 16 + quad * 4 + r) * FDIM + col]
                                = acc[s][nt][r];
                }
            }
            // fused attvec: per-row dot partial over this wave's cols
            #pragma unroll
            for (int s = 0; s < 4; ++s)
                #pragma unroll
                for (int r = 0; r < 4; ++r) {
                    float ps = 0.f, pd = 0.f;
                    #pragma unroll
                    for (int nt = 0; nt < 4; ++nt) {
                        ps = fmaf(acc[s][nt][r], asv[nt], ps);
                        pd = fmaf(acc[s][nt][r], adv[nt], pd);
                    }
                    #pragma unroll
                    for (int off = 1; off < 16; off <<= 1) {   // reduce over ln
                        ps += __shfl_xor(ps, off);
                        pd += __shfl_xor(pd, off);
                    }
                    if (ln == 0) {
                        int row = R0 + s * 16 + quad * 4 + r;
                        atomicAdd(a_s + row, ps);
                        atomicAdd(a_d + row, pd);
                    }
                }
            // seed out rows [R0, R0+64) with bias for k_attn's atomics
            int row = tid >> 2, q = tid & 3;
            float* op = out + (size_t)(R0 + row) * FDIM + q * 50;
            const float* bp = bias + q * 50;
            #pragma unroll
            for (int i = 0; i < 50; ++i) op[i] = bp[i];
        }
    }
}

// ---------------------------------------------------------------------------
// k_stats: per-row softmax stats. lrelu monotone => row max = lrelu(ad + max a_s).
// ---------------------------------------------------------------------------
__global__ __launch_bounds__(256) void k_stats(const float* __restrict__ a_s,
                                               const float* __restrict__ a_d,
                                               float* __restrict__ m_out,
                                               float* __restrict__ l_out)
{
    __shared__ float as_s[1024];
    const int tid = threadIdx.x;
    #pragma unroll
    for (int i = 0; i < 4; ++i) as_s[tid + i * 256] = a_s[tid + i * 256];
    __syncthreads();

    const int lane = tid & 63;
    const int wv   = tid >> 6;
    const int row  = blockIdx.x * 4 + wv;

    float mx = -1e30f;
    #pragma unroll
    for (int i = 0; i < 16; ++i) mx = fmaxf(mx, as_s[lane + i * 64]);
    #pragma unroll
    for (int off = 32; off; off >>= 1) mx = fmaxf(mx, __shfl_down(mx, off));
    mx = __shfl(mx, 0);

    const float ad = a_d[row];
    const float mi = lrelu(ad + mx);

    float sum = 0.f;
    #pragma unroll
    for (int i = 0; i < 16; ++i) {
        float s = lrelu(ad + as_s[lane + i * 64]);
        sum += __expf(s - mi);
    }
    #pragma unroll
    for (int off = 32; off; off >>= 1) sum += __shfl_down(sum, off);
    if (lane == 0) { m_out[row] = mi; l_out[row] = sum; }
}

// ---------------------------------------------------------------------------
// k_attn: out[i] += sum_j alpha[i][j] * h0[j] (bias pre-seeded by k_gemm).
// 512 blocks = 16 i-tiles x 4 col-chunks x 8 j-splits; waves sub-split j (32).
// lane = i; wave-uniform j => a_s[j] / h0-row chunk via s_load.
// LDS cross-wave reduce, then fp32 atomicAdd (8 blocks per address).
// ---------------------------------------------------------------------------
__global__ __launch_bounds__(256) void k_attn(const float* __restrict__ h0,
                                              const float* __restrict__ a_s,
                                              const float* __restrict__ a_d,
                                              const float* __restrict__ m_v,
                                              const float* __restrict__ l_v,
                                              float* __restrict__ out)
{
    __shared__ float red[4 * 64 * 50];   // 51,200 B
    const int tid  = threadIdx.x;
    const int lane = tid & 63;
    const int w    = __builtin_amdgcn_readfirstlane(tid >> 6);
    const int b    = blockIdx.x;
    const int it   = b >> 5;          // i-tile  [0,16)
    const int cc   = (b >> 3) & 3;    // c-chunk [0,4)
    const int js   = b & 7;           // j-split [0,8)
    const int i_g  = it * 64 + lane;
    const int c0   = cc * 50;

    const float ad = a_d[i_g];
    const float mi = m_v[i_g];
    const float rl = 1.0f / l_v[i_g];

    float acc[50];
    #pragma unroll
    for (int c = 0; c < 50; ++c) acc[c] = 0.f;

    const int j0 = js * 128 + w * 32;
    #pragma unroll 2
    for (int j = j0; j < j0 + 32; ++j) {
        float s = ad + a_s[j];                        // wave-uniform -> s_load
        s = (s > 0.f) ? s : NEG_SLOPE * s;
        float e = __expf(s - mi);
        const float* hr = h0 + (size_t)j * FDIM + c0; // wave-uniform -> s_load
        #pragma unroll
        for (int c = 0; c < 50; ++c)
            acc[c] = fmaf(hr[c], e, acc[c]);
    }

    #pragma unroll
    for (int c = 0; c < 50; ++c)
        red[(w * 64 + lane) * 50 + c] = acc[c] * rl;
    __syncthreads();

    for (int idx = tid; idx < 3200; idx += 256) {
        int i = idx / 50;
        int c = idx - i * 50;
        float v = red[idx] + red[3200 + idx] + red[6400 + idx] + red[9600 + idx];
        atomicAdd(out + (size_t)(it * 64 + i) * FDIM + c0 + c, v);
    }
}

// ---------------------------------------------------------------------------
extern "C" void kernel_launch(void* const* d_in, const int* in_sizes, int n_in,
                              void* d_out, int out_size, void* d_ws, size_t ws_size,
                              hipStream_t stream)
{
    const float* x       = (const float*)d_in[0];
    const float* W       = (const float*)d_in[1];
    const float* att_src = (const float*)d_in[2];
    const float* att_dst = (const float*)d_in[3];
    const float* bias    = (const float*)d_in[4];
    float* out = (float*)d_out;
    float* ws  = (float*)d_ws;

    float* h0  = ws;              // 204800 floats
    float* a_s = ws + 204800;     // 1024
    float* a_d = a_s + 1024;      // 1024
    float* m_i = a_d + 1024;      // 1024
    float* l_i = m_i + 1024;      // 1024
    unsigned short* fragW = (unsigned short*)((char*)d_ws + 835584);  // 114,688 B

    k_prep <<<NKT * NNT,  64, 0, stream>>>(W, fragW, a_s, a_d);
    k_gemm <<<MROWS / 128, 256, 0, stream>>>(x, fragW, bias, att_src, att_dst,
                                             out, h0, a_s, a_d);
    k_stats<<<NNODE / 4,  256, 0, stream>>>(a_s, a_d, m_i, l_i);
    k_attn <<<512,        256, 0, stream>>>(h0, a_s, a_d, m_i, l_i, out);
}

// Round 5
// 154.545 us; speedup vs baseline: 1.9401x; 1.0241x over previous
//
#include <hip/hip_runtime.h>

// Problem constants
#define BATCH 64
#define NNODE 1024
#define FDIM  200
#define MROWS (BATCH * NNODE)   // 65536
#define NEG_SLOPE 0.2f

#define NKT 7                   // k-tiles of 32 for W-GEMM (K 200 -> 224)
#define NNT 13                  // n-tiles of 16 (N 200 -> 208)

typedef short s16x8 __attribute__((ext_vector_type(8)));
typedef float f32x4 __attribute__((ext_vector_type(4)));

// ws layout (bytes):
//   h0frag : bf16 B-fragments of h0, 32 kt2 x 13 nt x 1024 B   [0, 425984)
//   a_s    : float[1024]  @ 425984   (atomic-accumulated; zeroed by k_prep)
//   a_d    : float[1024]  @ 430080
//   m_i    : float[1024]  @ 434176
//   l_i    : float[1024]  @ 438272
//   fragW  : bf16 B-fragments of W, 7 kt x 13 nt x 1024 B @ 442368 (93,184 B)

__device__ __forceinline__ unsigned int f2bf(float f) {
    unsigned int u = __float_as_uint(f);
    return (u + 0x7fffu + ((u >> 16) & 1u)) >> 16;
}
__device__ __forceinline__ unsigned int pack2(float a, float b) {
    return f2bf(a) | (f2bf(b) << 16);
}

// ---------------------------------------------------------------------------
// k_prep: W (200x200 fp32) -> bf16 B-fragments (16x16x32 layout), 224x208 pad.
//   frag b = kt*13+nt: lane holds B[k=kt*32+(lane>>4)*8+j][n=nt*16+(lane&15)]
// Block 0 zeroes a_s/a_d.
// ---------------------------------------------------------------------------
__global__ __launch_bounds__(64) void k_prep(const float* __restrict__ W,
                                             unsigned short* __restrict__ fragW,
                                             float* __restrict__ a_s,
                                             float* __restrict__ a_d)
{
    const int b    = blockIdx.x;          // 91 blocks
    const int kt   = b / NNT;
    const int nt   = b - kt * NNT;
    const int lane = threadIdx.x;
    const int n    = nt * 16 + (lane & 15);
    const int kb   = kt * 32 + (lane >> 4) * 8;

    s16x8 v;
    #pragma unroll
    for (int j = 0; j < 8; ++j) {
        int k = kb + j;
        float f = (k < FDIM && n < FDIM) ? W[k * FDIM + n] : 0.f;
        v[j] = (short)f2bf(f);
    }
    ((s16x8*)(fragW + (size_t)b * 512))[lane] = v;

    if (b == 0) {
        for (int i = lane; i < NNODE; i += 64) { a_s[i] = 0.f; a_d[i] = 0.f; }
    }
}

// ---------------------------------------------------------------------------
// k_gemm: h = x @ W. 4096 blocks x 64 thr (ONE wave, 16 rows, all 13 n-tiles).
// No LDS staging, no barriers: A-frag loaded straight from global
// (lane ln reads x[R0+ln][kt*32+quad*8 ..+8], contiguous 32 B) + bf16 pack.
// B-frags streamed from L2 (fragW). acc = 13 x f32x4.
//   R0 >= 1024: out = h + bias.
//   R0 <  1024: h -> h0frag (bf16 B-layout, via 1KB LDS transpose);
//               fused attvec partials (shuffle + atomics);
//               bias seeded into out rows (k_attn accumulates atomically).
// ---------------------------------------------------------------------------
__global__ __launch_bounds__(64) void k_gemm(const float* __restrict__ x,
                                             const unsigned short* __restrict__ fragW,
                                             const float* __restrict__ bias,
                                             const float* __restrict__ att_src,
                                             const float* __restrict__ att_dst,
                                             float* __restrict__ out,
                                             unsigned short* __restrict__ h0frag,
                                             float* __restrict__ a_s,
                                             float* __restrict__ a_d)
{
    __shared__ float scr[16][17];        // transpose scratch (R0<1024 only)
    const int lane = threadIdx.x;
    const int ln   = lane & 15;
    const int quad = lane >> 4;
    const int R0   = blockIdx.x * 16;

    f32x4 acc[NNT];
    #pragma unroll
    for (int nt = 0; nt < NNT; ++nt) acc[nt] = (f32x4){0.f, 0.f, 0.f, 0.f};

    const float* xrow = x + (size_t)(R0 + ln) * FDIM;

    #pragma unroll
    for (int kt = 0; kt < NKT; ++kt) {
        s16x8 a;
        if (kt < 6 || quad == 0) {       // kt==6: only k 192..199 valid (quad 0)
            const float4* ap = (const float4*)(xrow + kt * 32 + quad * 8);
            float4 f0 = ap[0], f1 = ap[1];
            unsigned int d0 = pack2(f0.x, f0.y), d1 = pack2(f0.z, f0.w);
            unsigned int d2 = pack2(f1.x, f1.y), d3 = pack2(f1.z, f1.w);
            unsigned int au[4] = {d0, d1, d2, d3};
            a = *(s16x8*)au;
        } else {
            a = (s16x8){0, 0, 0, 0, 0, 0, 0, 0};
        }
        #pragma unroll
        for (int nt = 0; nt < NNT; ++nt) {
            s16x8 b = *(const s16x8*)(fragW + ((size_t)(kt * NNT + nt) * 64 + lane) * 8);
            acc[nt] = __builtin_amdgcn_mfma_f32_16x16x32_bf16(a, b, acc[nt], 0, 0, 0);
        }
    }

    // D layout: col = nt*16 + ln, row = quad*4 + r
    if (R0 >= NNODE) {
        #pragma unroll
        for (int nt = 0; nt < NNT; ++nt) {
            int col = nt * 16 + ln;
            if (nt < 12 || ln < 8) {
                float bv = bias[col];
                #pragma unroll
                for (int r = 0; r < 4; ++r)
                    out[(size_t)(R0 + quad * 4 + r) * FDIM + col] = acc[nt][r] + bv;
            }
        }
    } else {
        // ---- (a) h0frag: transpose C-layout -> bf16 B-fragment halves.
        // Our 16 rows are j = R0..R0+15 = half of frag kt2 = R0>>5 (lo = which half).
        const int kt2 = R0 >> 5;
        const int lo  = (R0 >> 4) & 1;
        for (int nt = 0; nt < NNT; ++nt) {
            #pragma unroll
            for (int r = 0; r < 4; ++r) scr[quad * 4 + r][ln] = acc[nt][r];
            __syncthreads();
            if (lane < 32) {             // half-frag: lane = oct*16 + n
                int oct = lane >> 4, nl = lane & 15;
                uint4 dv;
                dv.x = pack2(scr[oct * 8 + 0][nl], scr[oct * 8 + 1][nl]);
                dv.y = pack2(scr[oct * 8 + 2][nl], scr[oct * 8 + 3][nl]);
                dv.z = pack2(scr[oct * 8 + 4][nl], scr[oct * 8 + 5][nl]);
                dv.w = pack2(scr[oct * 8 + 6][nl], scr[oct * 8 + 7][nl]);
                *(uint4*)(h0frag + ((size_t)(kt2 * NNT + nt) * 64 + lo * 32 + lane) * 8) = dv;
            }
            __syncthreads();
        }
        // ---- (b) fused attvec: per-row dots with att_src/att_dst
        float asv[NNT], adv[NNT];
        #pragma unroll
        for (int nt = 0; nt < NNT; ++nt) {
            int col = nt * 16 + ln;
            bool v = (nt < 12 || ln < 8);
            asv[nt] = v ? att_src[col] : 0.f;
            adv[nt] = v ? att_dst[col] : 0.f;
        }
        #pragma unroll
        for (int r = 0; r < 4; ++r) {
            float ps = 0.f, pd = 0.f;
            #pragma unroll
            for (int nt = 0; nt < NNT; ++nt) {
                ps = fmaf(acc[nt][r], asv[nt], ps);
                pd = fmaf(acc[nt][r], adv[nt], pd);
            }
            #pragma unroll
            for (int off = 1; off < 16; off <<= 1) {   // reduce over ln
                ps += __shfl_xor(ps, off);
                pd += __shfl_xor(pd, off);
            }
            if (ln == 0) {
                atomicAdd(a_s + R0 + quad * 4 + r, ps);
                atomicAdd(a_d + R0 + quad * 4 + r, pd);
            }
        }
        // ---- (c) bias-seed out rows [R0, R0+16)
        const float4* b4 = (const float4*)bias;       // 50 float4
        #pragma unroll
        for (int i = 0; i < 13; ++i) {
            int f = lane + i * 64;                    // 800 float4 total
            if (f < 800) {
                int row = f / 50, c4 = f - row * 50;
                ((float4*)out)[(size_t)(R0 + row) * 50 + c4] = b4[c4];
            }
        }
    }
}

// ---------------------------------------------------------------------------
// k_stats: per-row softmax stats. lrelu monotone => row max = lrelu(ad + max a_s).
// ---------------------------------------------------------------------------
__global__ __launch_bounds__(256) void k_stats(const float* __restrict__ a_s,
                                               const float* __restrict__ a_d,
                                               float* __restrict__ m_out,
                                               float* __restrict__ l_out)
{
    __shared__ float as_s[1024];
    const int tid = threadIdx.x;
    #pragma unroll
    for (int i = 0; i < 4; ++i) as_s[tid + i * 256] = a_s[tid + i * 256];
    __syncthreads();

    const int lane = tid & 63;
    const int wv   = tid >> 6;
    const int row  = blockIdx.x * 4 + wv;

    float mx = -1e30f;
    #pragma unroll
    for (int i = 0; i < 16; ++i) mx = fmaxf(mx, as_s[lane + i * 64]);
    #pragma unroll
    for (int off = 32; off; off >>= 1) mx = fmaxf(mx, __shfl_down(mx, off));
    mx = __shfl(mx, 0);

    const float ad = a_d[row];
    float mi = ad + mx; mi = (mi > 0.f) ? mi : NEG_SLOPE * mi;

    float sum = 0.f;
    #pragma unroll
    for (int i = 0; i < 16; ++i) {
        float s = ad + as_s[lane + i * 64];
        s = (s > 0.f) ? s : NEG_SLOPE * s;
        sum += __expf(s - mi);
    }
    #pragma unroll
    for (int off = 32; off; off >>= 1) sum += __shfl_down(sum, off);
    if (lane == 0) { m_out[row] = mi; l_out[row] = sum; }
}

// ---------------------------------------------------------------------------
// k_attn: out0 += alpha @ h0 via MFMA, alpha generated in-register.
// 256 blocks = 16 i-tiles(64 rows) x 16 j-splits(64 j). 4 waves: wave = 16 i-rows.
// A-frag: lane ln = i, k = quad*8+jj = j; e = exp(lrelu(ad_i + as_j) - m_i), bf16.
// B-frag: h0frag (contiguous dwordx4, L2-resident).
// Epilogue: acc * (1/l_i) atomicAdd into bias-seeded out.
// ---------------------------------------------------------------------------
__global__ __launch_bounds__(256) void k_attn(const unsigned short* __restrict__ h0frag,
                                              const float* __restrict__ a_s,
                                              const float* __restrict__ a_d,
                                              const float* __restrict__ m_v,
                                              const float* __restrict__ l_v,
                                              float* __restrict__ out)
{
    const int tid  = threadIdx.x;
    const int lane = tid & 63;
    const int w    = __builtin_amdgcn_readfirstlane(tid >> 6);
    const int ln   = lane & 15;
    const int quad = lane >> 4;
    const int it   = blockIdx.x >> 4;    // i-tile [0,16)
    const int ks   = blockIdx.x & 15;    // j-split [0,16)
    const int i0   = it * 64 + w * 16;
    const int jb   = ks * 64;

    const float ad = a_d[i0 + ln];
    const float mi = m_v[i0 + ln];

    f32x4 acc[NNT];
    #pragma unroll
    for (int nt = 0; nt < NNT; ++nt) acc[nt] = (f32x4){0.f, 0.f, 0.f, 0.f};

    #pragma unroll
    for (int h = 0; h < 2; ++h) {        // two kt2 of 32 j each
        const int kt2g = ks * 2 + h;
        const float4* ap = (const float4*)(a_s + jb + h * 32 + quad * 8);
        float4 f0 = ap[0], f1 = ap[1];
        float e[8] = {f0.x, f0.y, f0.z, f0.w, f1.x, f1.y, f1.z, f1.w};
        #pragma unroll
        for (int j = 0; j < 8; ++j) {
            float s = ad + e[j];
            s = (s > 0.f) ? s : NEG_SLOPE * s;
            e[j] = __expf(s - mi);
        }
        unsigned int au[4] = {pack2(e[0], e[1]), pack2(e[2], e[3]),
                              pack2(e[4], e[5]), pack2(e[6], e[7])};
        s16x8 afrag = *(s16x8*)au;
        #pragma unroll
        for (int nt = 0; nt < NNT; ++nt) {
            s16x8 b = *(const s16x8*)(h0frag + ((size_t)(kt2g * NNT + nt) * 64 + lane) * 8);
            acc[nt] = __builtin_amdgcn_mfma_f32_16x16x32_bf16(afrag, b, acc[nt], 0, 0, 0);
        }
    }

    float rl[4];
    #pragma unroll
    for (int r = 0; r < 4; ++r) rl[r] = 1.0f / l_v[i0 + quad * 4 + r];

    #pragma unroll
    for (int nt = 0; nt < NNT; ++nt) {
        int col = nt * 16 + ln;
        if (nt < 12 || ln < 8) {
            #pragma unroll
            for (int r = 0; r < 4; ++r)
                atomicAdd(out + (size_t)(i0 + quad * 4 + r) * FDIM + col,
                          acc[nt][r] * rl[r]);
        }
    }
}

// ---------------------------------------------------------------------------
extern "C" void kernel_launch(void* const* d_in, const int* in_sizes, int n_in,
                              void* d_out, int out_size, void* d_ws, size_t ws_size,
                              hipStream_t stream)
{
    const float* x       = (const float*)d_in[0];
    const float* W       = (const float*)d_in[1];
    const float* att_src = (const float*)d_in[2];
    const float* att_dst = (const float*)d_in[3];
    const float* bias    = (const float*)d_in[4];
    float* out = (float*)d_out;
    char*  wsb = (char*)d_ws;

    unsigned short* h0frag = (unsigned short*)(wsb + 0);       // 425,984 B
    float* a_s   = (float*)(wsb + 425984);
    float* a_d   = (float*)(wsb + 430080);
    float* m_i   = (float*)(wsb + 434176);
    float* l_i   = (float*)(wsb + 438272);
    unsigned short* fragW = (unsigned short*)(wsb + 442368);   // 93,184 B

    k_prep <<<NKT * NNT,  64, 0, stream>>>(W, fragW, a_s, a_d);
    k_gemm <<<MROWS / 16, 64, 0, stream>>>(x, fragW, bias, att_src, att_dst,
                                           out, h0frag, a_s, a_d);
    k_stats<<<NNODE / 4, 256, 0, stream>>>(a_s, a_d, m_i, l_i);
    k_attn <<<256,       256, 0, stream>>>(h0frag, a_s, a_d, m_i, l_i, out);
}

// Round 6
// 140.667 us; speedup vs baseline: 2.1315x; 1.0987x over previous
//
#include <hip/hip_runtime.h>

// Problem constants
#define BATCH 64
#define NNODE 1024
#define FDIM  200
#define MROWS (BATCH * NNODE)   // 65536
#define NEG_SLOPE 0.2f

#define NKT 7                   // k-tiles of 32 for W-GEMM (K 200 -> 224)
#define NNT 13                  // n-tiles of 16 (N 200 -> 208)

typedef short s16x8 __attribute__((ext_vector_type(8)));
typedef float f32x4 __attribute__((ext_vector_type(4)));

// ws layout (bytes):
//   h0frag : bf16 B-fragments of h0, 32 kt2 x 13 nt x 1024 B   [0, 425984)
//   a_s    : float[1024]  @ 425984
//   a_d    : float[1024]  @ 430080
//   m_i    : float[1024]  @ 434176
//   l_i    : float[1024]  @ 438272
//   fragW  : bf16 B-fragments of W, 7 kt x 13 nt x 1024 B @ 442368 (93,184 B)
//   wsv    : float[200] @ 535552   (W @ att_src)
//   wdv    : float[200] @ 536352   (W @ att_dst)

__device__ __forceinline__ unsigned int f2bf(float f) {
    unsigned int u = __float_as_uint(f);
    return (u + 0x7fffu + ((u >> 16) & 1u)) >> 16;
}
__device__ __forceinline__ unsigned int pack2(float a, float b) {
    return f2bf(a) | (f2bf(b) << 16);
}

// ---------------------------------------------------------------------------
// k_prep: blocks 0..90  : W -> bf16 B-fragments (16x16x32 layout), 224x208 pad
//         blocks 91..290: wsv[k]/wdv[k] = dot(W[k,:], att_src/att_dst)
// ---------------------------------------------------------------------------
__global__ __launch_bounds__(64) void k_prep(const float* __restrict__ W,
                                             const float* __restrict__ att_src,
                                             const float* __restrict__ att_dst,
                                             unsigned short* __restrict__ fragW,
                                             float* __restrict__ wsv,
                                             float* __restrict__ wdv)
{
    const int b    = blockIdx.x;
    const int lane = threadIdx.x;

    if (b < 91) {
        const int kt   = b / NNT;
        const int nt   = b - kt * NNT;
        const int n    = nt * 16 + (lane & 15);
        const int kb   = kt * 32 + (lane >> 4) * 8;
        s16x8 v;
        #pragma unroll
        for (int j = 0; j < 8; ++j) {
            int k = kb + j;
            float f = (k < FDIM && n < FDIM) ? W[k * FDIM + n] : 0.f;
            v[j] = (short)f2bf(f);
        }
        ((s16x8*)(fragW + (size_t)b * 512))[lane] = v;
    } else {
        const int kk = b - 91;               // [0, 200)
        const float* Wr = W + kk * FDIM;
        float ps = 0.f, pd = 0.f;
        #pragma unroll
        for (int i = 0; i < 4; ++i) {
            int n = lane + i * 64;
            if (n < FDIM) {
                float wv = Wr[n];
                ps = fmaf(wv, att_src[n], ps);
                pd = fmaf(wv, att_dst[n], pd);
            }
        }
        #pragma unroll
        for (int off = 32; off; off >>= 1) {
            ps += __shfl_down(ps, off);
            pd += __shfl_down(pd, off);
        }
        if (lane == 0) { wsv[kk] = ps; wdv[kk] = pd; }
    }
}

// ---------------------------------------------------------------------------
// k_av: a_s = x0 @ wsv, a_d = x0 @ wdv  (reassociated (x@W)@att = x@(W@att)).
// One wave per row, coalesced.
// ---------------------------------------------------------------------------
__global__ __launch_bounds__(256) void k_av(const float* __restrict__ x,
                                            const float* __restrict__ wsv,
                                            const float* __restrict__ wdv,
                                            float* __restrict__ a_s,
                                            float* __restrict__ a_d)
{
    const int tid  = threadIdx.x;
    const int lane = tid & 63;
    const int row  = blockIdx.x * 4 + (tid >> 6);
    const float* xr = x + (size_t)row * FDIM;
    float ss = 0.f, sd = 0.f;
    for (int k = lane; k < FDIM; k += 64) {
        float xv = xr[k];
        ss = fmaf(xv, wsv[k], ss);
        sd = fmaf(xv, wdv[k], sd);
    }
    #pragma unroll
    for (int off = 32; off; off >>= 1) {
        ss += __shfl_down(ss, off);
        sd += __shfl_down(sd, off);
    }
    if (lane == 0) { a_s[row] = ss; a_d[row] = sd; }
}

// ---------------------------------------------------------------------------
// k_gemm: h = x @ W. 4096 blocks x 64 thr (one wave, 16 rows, all 13 n-tiles).
// Software-pipelined: B-frags register-double-buffered (bn loaded for kt+1
// BEFORE the kt MFMAs), A raw loads 4-deep rolling prefetch. No LDS staging.
//   R0 >= 1024: out = h + bias.
//   R0 <  1024: h -> h0frag (bf16 B-layout via LDS transpose) only.
// ---------------------------------------------------------------------------
__global__ __launch_bounds__(64) void k_gemm(const float* __restrict__ x,
                                             const unsigned short* __restrict__ fragW,
                                             const float* __restrict__ bias,
                                             float* __restrict__ out,
                                             unsigned short* __restrict__ h0frag)
{
    __shared__ float scr[16][17];        // transpose scratch (R0<1024 only)
    const int lane = threadIdx.x;
    const int ln   = lane & 15;
    const int quad = lane >> 4;
    const int R0   = blockIdx.x * 16;

    f32x4 acc[NNT];
    #pragma unroll
    for (int nt = 0; nt < NNT; ++nt) acc[nt] = (f32x4){0.f, 0.f, 0.f, 0.f};

    const float* xrow = x + (size_t)(R0 + ln) * FDIM;

    // rolling A prefetch (raw fp32), 4 deep
    float4 ar[NKT][2];
    #pragma unroll
    for (int kt = 0; kt < 4; ++kt) {
        const float4* ap = (const float4*)(xrow + kt * 32 + quad * 8);
        ar[kt][0] = ap[0]; ar[kt][1] = ap[1];
    }

    // B double buffer
    s16x8 bc[NNT], bn[NNT];
    #pragma unroll
    for (int nt = 0; nt < NNT; ++nt)
        bc[nt] = *(const s16x8*)(fragW + ((size_t)nt * 64 + lane) * 8);

    #pragma unroll
    for (int kt = 0; kt < NKT; ++kt) {
        // prefetch next B tile before this tile's MFMAs
        if (kt < NKT - 1) {
            #pragma unroll
            for (int nt = 0; nt < NNT; ++nt)
                bn[nt] = *(const s16x8*)(fragW +
                    ((size_t)((kt + 1) * NNT + nt) * 64 + lane) * 8);
        }
        // prefetch A 4 ahead
        if (kt + 4 < NKT) {
            int ka = kt + 4;
            if (ka < 6) {
                const float4* ap = (const float4*)(xrow + ka * 32 + quad * 8);
                ar[ka][0] = ap[0]; ar[ka][1] = ap[1];
            } else {                      // kt==6: only quad 0 in-bounds
                if (quad == 0) {
                    const float4* ap = (const float4*)(xrow + ka * 32);
                    ar[ka][0] = ap[0]; ar[ka][1] = ap[1];
                } else {
                    ar[ka][0] = make_float4(0.f, 0.f, 0.f, 0.f);
                    ar[ka][1] = make_float4(0.f, 0.f, 0.f, 0.f);
                }
            }
        }
        // pack current A frag
        float4 f0 = ar[kt][0], f1 = ar[kt][1];
        unsigned int au[4] = {pack2(f0.x, f0.y), pack2(f0.z, f0.w),
                              pack2(f1.x, f1.y), pack2(f1.z, f1.w)};
        s16x8 a = *(s16x8*)au;
        #pragma unroll
        for (int nt = 0; nt < NNT; ++nt)
            acc[nt] = __builtin_amdgcn_mfma_f32_16x16x32_bf16(a, bc[nt], acc[nt], 0, 0, 0);
        if (kt < NKT - 1) {
            #pragma unroll
            for (int nt = 0; nt < NNT; ++nt) bc[nt] = bn[nt];
        }
    }

    // D layout: col = nt*16 + ln, row = quad*4 + r
    if (R0 >= NNODE) {
        #pragma unroll
        for (int nt = 0; nt < NNT; ++nt) {
            int col = nt * 16 + ln;
            if (nt < 12 || ln < 8) {
                float bv = bias[col];
                #pragma unroll
                for (int r = 0; r < 4; ++r)
                    out[(size_t)(R0 + quad * 4 + r) * FDIM + col] = acc[nt][r] + bv;
            }
        }
    } else {
        // h0frag: transpose C-layout -> bf16 B-fragment halves (kt2 = R0>>5).
        const int kt2 = R0 >> 5;
        const int lo  = (R0 >> 4) & 1;
        for (int nt = 0; nt < NNT; ++nt) {
            #pragma unroll
            for (int r = 0; r < 4; ++r) scr[quad * 4 + r][ln] = acc[nt][r];
            __syncthreads();
            if (lane < 32) {             // half-frag: lane = oct*16 + n
                int oct = lane >> 4, nl = lane & 15;
                uint4 dv;
                dv.x = pack2(scr[oct * 8 + 0][nl], scr[oct * 8 + 1][nl]);
                dv.y = pack2(scr[oct * 8 + 2][nl], scr[oct * 8 + 3][nl]);
                dv.z = pack2(scr[oct * 8 + 4][nl], scr[oct * 8 + 5][nl]);
                dv.w = pack2(scr[oct * 8 + 6][nl], scr[oct * 8 + 7][nl]);
                *(uint4*)(h0frag + ((size_t)(kt2 * NNT + nt) * 64 + lo * 32 + lane) * 8) = dv;
            }
            __syncthreads();
        }
    }
}

// ---------------------------------------------------------------------------
// k_stats: per-row softmax stats. lrelu monotone => row max = lrelu(ad + max a_s).
// ---------------------------------------------------------------------------
__global__ __launch_bounds__(256) void k_stats(const float* __restrict__ a_s,
                                               const float* __restrict__ a_d,
                                               float* __restrict__ m_out,
                                               float* __restrict__ l_out)
{
    __shared__ float as_s[1024];
    const int tid = threadIdx.x;
    #pragma unroll
    for (int i = 0; i < 4; ++i) as_s[tid + i * 256] = a_s[tid + i * 256];
    __syncthreads();

    const int lane = tid & 63;
    const int row  = blockIdx.x * 4 + (tid >> 6);

    float mx = -1e30f;
    #pragma unroll
    for (int i = 0; i < 16; ++i) mx = fmaxf(mx, as_s[lane + i * 64]);
    #pragma unroll
    for (int off = 32; off; off >>= 1) mx = fmaxf(mx, __shfl_down(mx, off));
    mx = __shfl(mx, 0);

    const float ad = a_d[row];
    float mi = ad + mx; mi = (mi > 0.f) ? mi : NEG_SLOPE * mi;

    float sum = 0.f;
    #pragma unroll
    for (int i = 0; i < 16; ++i) {
        float s = ad + as_s[lane + i * 64];
        s = (s > 0.f) ? s : NEG_SLOPE * s;
        sum += __expf(s - mi);
    }
    #pragma unroll
    for (int off = 32; off; off >>= 1) sum += __shfl_down(sum, off);
    if (lane == 0) { m_out[row] = mi; l_out[row] = sum; }
}

// ---------------------------------------------------------------------------
// k_attn: out0 = (alpha @ h0) + bias via MFMA, NO atomics.
// 208 blocks = 16 i-tiles x 13 nt; 4 waves, wave = 16 i-rows, ALL 1024 j.
// Per kt2: alpha frag generated in-register (exp(lrelu(ad+as)-m), bf16),
// one h0frag B-load, one MFMA (two alternating acc chains). Direct store.
// ---------------------------------------------------------------------------
__global__ __launch_bounds__(256) void k_attn(const unsigned short* __restrict__ h0frag,
                                              const float* __restrict__ a_s,
                                              const float* __restrict__ a_d,
                                              const float* __restrict__ m_v,
                                              const float* __restrict__ l_v,
                                              const float* __restrict__ bias,
                                              float* __restrict__ out)
{
    const int tid  = threadIdx.x;
    const int lane = tid & 63;
    const int w    = __builtin_amdgcn_readfirstlane(tid >> 6);
    const int ln   = lane & 15;
    const int quad = lane >> 4;
    const int it   = blockIdx.x / NNT;
    const int nt   = blockIdx.x - it * NNT;
    const int i0   = it * 64 + w * 16;

    const float ad = a_d[i0 + ln];
    const float mi = m_v[i0 + ln];

    f32x4 accA = (f32x4){0.f, 0.f, 0.f, 0.f};
    f32x4 accB = (f32x4){0.f, 0.f, 0.f, 0.f};

    #pragma unroll
    for (int kt2 = 0; kt2 < 32; ++kt2) {
        const float4* ap = (const float4*)(a_s + kt2 * 32 + quad * 8);
        float4 f0 = ap[0], f1 = ap[1];
        float e[8] = {f0.x, f0.y, f0.z, f0.w, f1.x, f1.y, f1.z, f1.w};
        #pragma unroll
        for (int j = 0; j < 8; ++j) {
            float s = ad + e[j];
            s = (s > 0.f) ? s : NEG_SLOPE * s;
            e[j] = __expf(s - mi);
        }
        unsigned int au[4] = {pack2(e[0], e[1]), pack2(e[2], e[3]),
                              pack2(e[4], e[5]), pack2(e[6], e[7])};
        s16x8 afrag = *(s16x8*)au;
        s16x8 b = *(const s16x8*)(h0frag + ((size_t)(kt2 * NNT + nt) * 64 + lane) * 8);
        if (kt2 & 1) accB = __builtin_amdgcn_mfma_f32_16x16x32_bf16(afrag, b, accB, 0, 0, 0);
        else         accA = __builtin_amdgcn_mfma_f32_16x16x32_bf16(afrag, b, accA, 0, 0, 0);
    }

    const int col = nt * 16 + ln;
    if (nt < 12 || ln < 8) {
        float bv = bias[col];
        #pragma unroll
        for (int r = 0; r < 4; ++r) {
            float rl = 1.0f / l_v[i0 + quad * 4 + r];
            out[(size_t)(i0 + quad * 4 + r) * FDIM + col]
                = (accA[r] + accB[r]) * rl + bv;
        }
    }
}

// ---------------------------------------------------------------------------
extern "C" void kernel_launch(void* const* d_in, const int* in_sizes, int n_in,
                              void* d_out, int out_size, void* d_ws, size_t ws_size,
                              hipStream_t stream)
{
    const float* x       = (const float*)d_in[0];
    const float* W       = (const float*)d_in[1];
    const float* att_src = (const float*)d_in[2];
    const float* att_dst = (const float*)d_in[3];
    const float* bias    = (const float*)d_in[4];
    float* out = (float*)d_out;
    char*  wsb = (char*)d_ws;

    unsigned short* h0frag = (unsigned short*)(wsb + 0);       // 425,984 B
    float* a_s   = (float*)(wsb + 425984);
    float* a_d   = (float*)(wsb + 430080);
    float* m_i   = (float*)(wsb + 434176);
    float* l_i   = (float*)(wsb + 438272);
    unsigned short* fragW = (unsigned short*)(wsb + 442368);   // 93,184 B
    float* wsv   = (float*)(wsb + 535552);
    float* wdv   = (float*)(wsb + 536352);

    k_prep <<<291,        64, 0, stream>>>(W, att_src, att_dst, fragW, wsv, wdv);
    k_av   <<<NNODE / 4, 256, 0, stream>>>(x, wsv, wdv, a_s, a_d);
    k_stats<<<NNODE / 4, 256, 0, stream>>>(a_s, a_d, m_i, l_i);
    k_gemm <<<MROWS / 16, 64, 0, stream>>>(x, fragW, bias, out, h0frag);
    k_attn <<<16 * NNT,  256, 0, stream>>>(h0frag, a_s, a_d, m_i, l_i, bias, out);
}